// Round 4
// baseline (293.742 us; speedup 1.0000x reference)
//
#include <hip/hip_runtime.h>

// Problem constants: B=16, S=2048, D=1024, P=8192, R=16, NL=64, span<=31
#define S_LEN      2048
#define D_DIM      1024
#define R_DIM      16
#define OUT_STRIDE 2064          // 2*D + R
#define NBUCK      8192          // (B*S)>>2 coarse sort buckets (32 KB LDS hist)
#define BPT        8             // buckets per thread in the scan (NBUCK/1024)
#define G          16            // sorted jobs per gather group (traffic ~ 2+31/G)
#define NR         4             // rows per LDS chunk
#define HW         512           // column half width (floats)

// ---------------------------------------------------------------------------
// Fused counting sort of the 2P span-jobs by coarse start bucket
// ((b*S + s) >> 2). One workgroup, everything in LDS.
__global__ __launch_bounds__(1024) void sort_jobs(
    const int* __restrict__ bidx, const int* __restrict__ e1s,
    const int* __restrict__ e2s, int* __restrict__ sorted, int njobs)
{
    __shared__ int hist[NBUCK];   // 32 KB
    __shared__ int part[1024];    // 4 KB
    const int t = threadIdx.x;

#pragma unroll
    for (int i = 0; i < BPT; ++i) hist[t * BPT + i] = 0;
    __syncthreads();

    for (int j = t; j < njobs; j += 1024) {
        const int p = j >> 1;
        const int s = (j & 1) ? e2s[p] : e1s[p];
        atomicAdd(&hist[(bidx[p] * S_LEN + s) >> 2], 1);
    }
    __syncthreads();

    int v[BPT];
    int sum = 0;
#pragma unroll
    for (int i = 0; i < BPT; ++i) { v[i] = hist[t * BPT + i]; sum += v[i]; }
    part[t] = sum;
    __syncthreads();
    for (int off = 1; off < 1024; off <<= 1) {
        int x = (t >= off) ? part[t - off] : 0;
        __syncthreads();
        part[t] += x;
        __syncthreads();
    }
    int run = (t == 0) ? 0 : part[t - 1];
#pragma unroll
    for (int i = 0; i < BPT; ++i) { int c = v[i]; hist[t * BPT + i] = run; run += c; }
    __syncthreads();

    for (int j = t; j < njobs; j += 1024) {
        const int p = j >> 1;
        const int s = (j & 1) ? e2s[p] : e1s[p];
        const int pos = atomicAdd(&hist[(bidx[p] * S_LEN + s) >> 2], 1);
        sorted[pos] = j;
    }
}

// ---------------------------------------------------------------------------
__device__ __forceinline__ void load16_lds(const float* g_, float* l_) {
    __builtin_amdgcn_global_load_lds(
        (const __attribute__((address_space(1))) void*)g_,
        (__attribute__((address_space(3))) void*)l_, 16, 0, 0);
}

// ---------------------------------------------------------------------------
// Grouped gather v7: GROUP=16. Evidence from v3-v6: all structures converge
// to ~7.5-10 TB/s of L2/L3 window traffic (620 MB at G=4) -- supply-bound,
// not latency-bound. Traffic ~ njobs*4KB*(2 + 31/G): G=16 cuts demand 2.5x
// for 64 VGPRs of accumulator. Structure = v5's proven LDS double-buffer
// (stage(c+1) -> compute(c) -> __syncthreads), col-split 128-thread blocks:
// 2048 blocks, 16 KB LDS -> ~10 blocks/CU. Weights are wave-uniform scalar
// selects (SGPR) feeding v_fmac; out-of-window rows get weight 0; tail rows
// clamped to the last window row.
__global__ __launch_bounds__(128) void gather_g16(
    const float* __restrict__ tok,     // [B*S, D] fp32
    const int*   __restrict__ sorted,  // [2P] sorted job ids
    const int*   __restrict__ bidx,
    const int*   __restrict__ e1s, const int* __restrict__ e1e,
    const int*   __restrict__ e2s, const int* __restrict__ e2e,
    const int*   __restrict__ ridx,
    const float* __restrict__ rtab,    // [NL, R]
    float*       __restrict__ out)     // [P, 2D+R]
{
    __shared__ float buf[2][NR * HW];   // 2 x 8 KB = 16 KB

    const int blk = blockIdx.x;
    // XCD swizzle: contiguous work ranges per XCD (grid 2048, %8==0, bijective)
    const int w  = (blk & 7) * (gridDim.x >> 3) + (blk >> 3);
    const int g  = w >> 1;             // job group (16 sorted jobs)
    const int ch = w & 1;              // column half: cols [ch*512, ch*512+512)
    const int t  = threadIdx.x;        // 0..127, 4 cols each
    const int wv = t >> 6;             // wave id 0..1
    const int ln = t & 63;

    // group metadata -> SGPR arrays (fully static indexing everywhere)
    int   js[G], je[G], jd[G], jrel[G];
    float jw[G];
    int mins = 0x7fffffff, maxe = 0;
#pragma unroll
    for (int i = 0; i < G; ++i) {
        const int id = __builtin_amdgcn_readfirstlane(sorted[g * G + i]);
        const int p  = id >> 1;
        const int h  = id & 1;
        const int b  = __builtin_amdgcn_readfirstlane(bidx[p]);
        const int s  = __builtin_amdgcn_readfirstlane(h ? e2s[p] : e1s[p]);
        const int e  = __builtin_amdgcn_readfirstlane(h ? e2e[p] : e1e[p]);
        js[i]   = b * S_LEN + s;
        je[i]   = b * S_LEN + e;
        jw[i]   = 1.0f / (float)(e - s);
        jd[i]   = p * OUT_STRIDE + h * D_DIM;   // output base (floats)
        jrel[i] = (h == 0) ? p : -1;            // pair whose rel row we write
        mins = min(mins, js[i]);
        maxe = max(maxe, je[i]);
    }

    const int nrows = maxe - mins;             // >= 1
    const int rmaxg = maxe - 1;                // last valid global row
    const int niter = (nrows + NR - 1) / NR;

    // stage chunk c into buffer bi: wave wv DMAs chunk-rows {2wv, 2wv+1}
    auto stage = [&](int bi, int c) {
#pragma unroll
        for (int rr = 0; rr < 2; ++rr) {
            const int r    = wv * 2 + rr;
            const int grow = min(mins + c * NR + r, rmaxg);
            const float* src = tok + (size_t)grow * D_DIM + ch * HW + ln * 4;
            float* dst = &buf[bi][r * HW];
            load16_lds(src,       dst);
            load16_lds(src + 256, dst + 256);
        }
    };

    stage(0, 0);

    float4 acc[G];
#pragma unroll
    for (int i = 0; i < G; ++i) acc[i] = make_float4(0.f, 0.f, 0.f, 0.f);

    __syncthreads();                           // chunk 0 landed

    for (int c = 0; c < niter; ++c) {
        if (c + 1 < niter) stage((c + 1) & 1, c + 1);   // overlap next DMA

        const int cb  = c & 1;
        const int gr0 = mins + c * NR;
#pragma unroll
        for (int r = 0; r < NR; ++r) {
            const float4 v = *reinterpret_cast<const float4*>(
                &buf[cb][r * HW + t * 4]);
            const int gr = gr0 + r;
#pragma unroll
            for (int i = 0; i < G; ++i) {      // wave-uniform scalar weights
                const float wt = (gr >= js[i] && gr < je[i]) ? jw[i] : 0.f;
                acc[i].x += v.x * wt;
                acc[i].y += v.y * wt;
                acc[i].z += v.z * wt;
                acc[i].w += v.w * wt;
            }
        }
        __syncthreads();   // drains next-chunk DMA; releases buf[cb]
    }

#pragma unroll
    for (int i = 0; i < G; ++i) {
        float* dst = out + (size_t)jd[i] + ch * HW + t * 4;
        *reinterpret_cast<float4*>(dst) = acc[i];
        if (ch == 0 && jrel[i] >= 0 && t < 4) {   // rel row once per pair
            const float4 rv = *reinterpret_cast<const float4*>(
                rtab + ridx[jrel[i]] * R_DIM + t * 4);
            *reinterpret_cast<float4*>(
                out + (size_t)jrel[i] * OUT_STRIDE + 2 * D_DIM + t * 4) = rv;
        }
    }
}

// ---------------------------------------------------------------------------
extern "C" void kernel_launch(void* const* d_in, const int* in_sizes, int n_in,
                              void* d_out, int out_size, void* d_ws, size_t ws_size,
                              hipStream_t stream) {
    const float* tok  = (const float*)d_in[0];
    const int*   bidx = (const int*)d_in[1];
    const int*   e1s  = (const int*)d_in[2];
    const int*   e1e  = (const int*)d_in[3];
    const int*   e2s  = (const int*)d_in[4];
    const int*   e2e  = (const int*)d_in[5];
    const int*   ridx = (const int*)d_in[6];
    const float* rtab = (const float*)d_in[7];
    float*       out  = (float*)d_out;

    const int P     = in_sizes[1];   // 8192
    const int njobs = 2 * P;         // 16384

    int* sorted = (int*)d_ws;        // njobs ints

    sort_jobs<<<1, 1024, 0, stream>>>(bidx, e1s, e2s, sorted, njobs);

    const int nblocks = (njobs / G) * 2;        // 2 col-halves per group
    gather_g16<<<nblocks, 128, 0, stream>>>(
        tok, sorted, bidx, e1s, e1e, e2s, e2e, ridx, rtab, out);
}